// Round 5
// baseline (502.776 us; speedup 1.0000x reference)
//
#include <hip/hip_runtime.h>
#include <hip/hip_bf16.h>

#define D_MODEL 768
#define N_HEADS 12
#define D_K     64
#define NEG_INF (-1e9f)
#define KS_PAD  72    // Ks row stride (shorts): 144 B
#define SCALE_Q 0.1803368801111154f  // 0.125 * log2(e): exp2-domain softmax
#define W_ELEMS (D_MODEL * D_MODEL)

typedef __attribute__((ext_vector_type(8))) short          bf16x8;
typedef __attribute__((ext_vector_type(4))) float          floatx4;
typedef __attribute__((ext_vector_type(4))) unsigned short ushortx4;
typedef __attribute__((ext_vector_type(2))) unsigned int   uintx2;
typedef __attribute__((ext_vector_type(4))) unsigned int   uintx4;

static __device__ __forceinline__ unsigned short f2bf(float f) {
    unsigned u = __builtin_bit_cast(unsigned, f);
    u += 0x7FFFu + ((u >> 16) & 1u);
    return (unsigned short)(u >> 16);
}

// async 16B/lane global->LDS (lds dest = wave-uniform base + lane*16)
static __device__ __forceinline__ void gload_lds16(const void* g, void* l) {
    __builtin_amdgcn_global_load_lds(
        (const __attribute__((address_space(1))) void*)g,
        (__attribute__((address_space(3))) void*)l, 16, 0, 0);
}

// ---------------------------------------------------------------------------
// fp32 -> bf16 converters.
// ---------------------------------------------------------------------------
__global__ __launch_bounds__(256) void convert_w4(
    const float* __restrict__ W0, const float* __restrict__ W1,
    const float* __restrict__ W2, const float* __restrict__ W3,
    unsigned short* __restrict__ out)
{
    const float* src[4] = {W0, W1, W2, W3};
    const float* W = src[blockIdx.y];
    unsigned short* o = out + (size_t)blockIdx.y * W_ELEMS;
    const int i = (blockIdx.x * 256 + threadIdx.x) * 4;
    float4 v = *(const float4*)(W + i);
    ushortx4 h = { f2bf(v.x), f2bf(v.y), f2bf(v.z), f2bf(v.w) };
    *(ushortx4*)(o + i) = h;
}

__global__ __launch_bounds__(256) void convert_a3(
    const float* __restrict__ A0, const float* __restrict__ A1,
    const float* __restrict__ A2,
    unsigned short* __restrict__ O0, unsigned short* __restrict__ O1,
    unsigned short* __restrict__ O2)
{
    const int z = blockIdx.y;
    const float* A = (z == 0) ? A0 : (z == 1) ? A1 : A2;
    unsigned short* O = (z == 0) ? O0 : (z == 1) ? O1 : O2;
    const int i = (blockIdx.x * 256 + threadIdx.x) * 4;
    float4 v = *(const float4*)(A + i);
    ushortx4 h = { f2bf(v.x), f2bf(v.y), f2bf(v.z), f2bf(v.w) };
    *(ushortx4*)(O + i) = h;
}

// ---------------------------------------------------------------------------
// C[M,N] = A[M,K] @ W[N,K]^T + bias[N];  A, W bf16; K = N = 768.
// m97 shape: 128x128 block tile, BK=32, 4 waves in 2x2 (64x64/wave),
// acc[4][4] -> 32 MFMA per barrier pair. Async global_load_lds staging.
// MFMA operand-swapped: D rows (quad*4+r) = n, cols (l16) = m -> vectorized
// stores along n. QKV: grid.z selects {Q(scale,bf16), K(bf16), V(->VpT)}.
// !QKV: single fp32 output (the final O @ Wo^T).
// ---------------------------------------------------------------------------
template <bool QKV>
__global__ __launch_bounds__(256) void gemm128(
    const unsigned short* __restrict__ A0, const unsigned short* __restrict__ A1,
    const unsigned short* __restrict__ A2,
    const unsigned short* __restrict__ W0, const unsigned short* __restrict__ W1,
    const unsigned short* __restrict__ W2,
    const float* __restrict__ b0, const float* __restrict__ b1,
    const float* __restrict__ b2,
    void* __restrict__ C0, void* __restrict__ C1, void* __restrict__ C2,
    int S)
{
    __shared__ __align__(16) unsigned short As[128 * 32];
    __shared__ __align__(16) unsigned short Bs[128 * 32];

    const int z = QKV ? blockIdx.z : 0;
    const unsigned short* A = (z == 0) ? A0 : (z == 1) ? A1 : A2;
    const unsigned short* W = (z == 0) ? W0 : (z == 1) ? W1 : W2;
    const float* bias       = (z == 0) ? b0 : (z == 1) ? b1 : b2;
    void* C                 = (z == 0) ? C0 : (z == 1) ? C1 : C2;
    const float scale = (QKV && z == 0) ? SCALE_Q : 1.0f;
    const int mode = QKV ? ((z == 2) ? 3 : 1) : 0;   // 3=VpT, 1=bf16, 0=fp32

    const int tid  = threadIdx.x;
    const int wave = tid >> 6;
    const int lane = tid & 63;
    const int quad = lane >> 4;
    const int l16  = lane & 15;
    const int m0 = blockIdx.x * 128;
    const int n0 = blockIdx.y * 128;
    const int wm = (wave & 1) * 64;
    const int wn = (wave >> 1) * 64;
    const int sr = lane >> 2;          // staging row within 16-row group
    const int sc = (lane & 3) << 3;    // staging col chunk (8 shorts = 16 B)

    const floatx4 zero4 = {0.f, 0.f, 0.f, 0.f};
    floatx4 acc[4][4];
    #pragma unroll
    for (int i = 0; i < 4; ++i)
        #pragma unroll
        for (int j = 0; j < 4; ++j) acc[i][j] = zero4;

    for (int k0 = 0; k0 < D_MODEL; k0 += 32) {
        // wave stages A rows [32w,32w+32) and W rows [32w,32w+32), 16/call
        #pragma unroll
        for (int c = 0; c < 2; ++c) {
            const int row = wave * 32 + c * 16;
            gload_lds16(A + (size_t)(m0 + row + sr) * D_MODEL + k0 + sc,
                        As + row * 32);
            gload_lds16(W + (size_t)(n0 + row + sr) * D_MODEL + k0 + sc,
                        Bs + row * 32);
        }
        __syncthreads();

        bf16x8 af[4], bfr[4];
        #pragma unroll
        for (int i = 0; i < 4; ++i)
            af[i] = *(const bf16x8*)(As + (wm + i * 16 + l16) * 32 + quad * 8);
        #pragma unroll
        for (int j = 0; j < 4; ++j)
            bfr[j] = *(const bf16x8*)(Bs + (wn + j * 16 + l16) * 32 + quad * 8);
        #pragma unroll
        for (int i = 0; i < 4; ++i)
            #pragma unroll
            for (int j = 0; j < 4; ++j)
                acc[i][j] = __builtin_amdgcn_mfma_f32_16x16x32_bf16(
                    bfr[j], af[i], acc[i][j], 0, 0, 0);   // swapped: rows=n
        __syncthreads();
    }

    // epilogue: D[i][j] rows (quad*4+r) = n, cols (l16) = m
    #pragma unroll
    for (int i = 0; i < 4; ++i) {
        const int m = m0 + wm + i * 16 + l16;
        #pragma unroll
        for (int j = 0; j < 4; ++j) {
            const int nb = n0 + wn + j * 16 + quad * 4;
            const float4 bv = *(const float4*)(bias + nb);
            float v0 = (acc[i][j][0] + bv.x) * scale;
            float v1 = (acc[i][j][1] + bv.y) * scale;
            float v2 = (acc[i][j][2] + bv.z) * scale;
            float v3 = (acc[i][j][3] + bv.w) * scale;
            if (mode == 0) {
                float4 o = {v0, v1, v2, v3};
                *(float4*)((float*)C + (size_t)m * D_MODEL + nb) = o;
            } else if (mode == 1) {
                ushortx4 o = {f2bf(v0), f2bf(v1), f2bf(v2), f2bf(v3)};
                *(ushortx4*)((unsigned short*)C + (size_t)m * D_MODEL + nb) = o;
            } else {
                // VpT[(bb*H + h)*64 + d][s]: 4 consecutive d, fixed s=m
                const int bb = m / S, s = m - bb * S;
                const int hh = nb >> 6, d = nb & 63;
                unsigned short* base = (unsigned short*)C +
                    ((size_t)(bb * N_HEADS + hh) * D_K + d) * S + s;
                base[0]         = f2bf(v0);
                base[(size_t)S]     = f2bf(v1);
                base[(size_t)S * 2] = f2bf(v2);
                base[(size_t)S * 3] = f2bf(v3);
            }
        }
    }
}

// ---------------------------------------------------------------------------
// Causal flash attention: 128-key k-iterations, load-balanced tile pairs
// (p, 63-p) -> every block runs exactly 33 k-iterations (R2 pairing, grid
// 768 = exactly 3 blocks/CU). XCD swizzle: bh = L%24 keeps each (b,h)'s 32
// blocks on one XCD's L2. Operand-swapped QK^T (rows=keys, cols=q),
// P-in-registers via permlane32/16_swap (T12), row-sum via ones-MFMA,
// fixed-m exp2-domain softmax.
//
// R5 changes vs R2:
//  - V is read DIRECTLY from global in PV (Vts LDS buffer dropped). All 4
//    waves read the same 16KB V-tile -> L1 serves the amplification; VpT is
//    L2-resident per XCD (bh%24 affinity). Removes half the staging and
//    half the LDS traffic.
//  - Ks (+mskf) double-buffered with T14 issue-early/write-late: K[kt+1]
//    global loads issue at the TOP of iter kt, ds_writes to Ks[cur^1] at
//    the BOTTOM, ONE barrier per iteration (vs 2). Staging latency hides
//    under QK^T+softmax+PV. (R1 failed because it committed at the top,
//    serializing vmcnt(0) before compute, and kept both barriers.)
// ---------------------------------------------------------------------------
__global__ __launch_bounds__(256) void flash_attn(
    const unsigned short* __restrict__ Qp,
    const unsigned short* __restrict__ Kp,
    const unsigned short* __restrict__ VpT,
    const int* __restrict__ mask,
    unsigned short* __restrict__ O,   // bf16 [B*S, D_MODEL]
    int S)
{
    __shared__ __align__(16) unsigned short Ks[2][128 * KS_PAD];  // [key][d]
    __shared__ __align__(16) float mskf[2][128];

    const int L  = blockIdx.x;
    const int bh = L % 24;
    const int p  = L / 24;
    const int h  = bh % 12;
    const int b  = bh / 12;
    const int nqt = S >> 6;
    const int tid  = threadIdx.x;
    const int wave = tid >> 6;
    const int lane = tid & 63;
    const int quad = lane >> 4;
    const int l16  = lane & 15;

    const unsigned short* Kbase = Kp  + (size_t)(b * S) * D_MODEL + h * D_K;
    const unsigned short* Vbase = VpT + (size_t)(b * N_HEADS + h) * D_K * S;
    const int* mbase = mask + b * S;

    const floatx4 zero4 = {0.f, 0.f, 0.f, 0.f};
    const short one_bf = (short)0x3F80;  // bf16 1.0
    const bf16x8 ones = {one_bf, one_bf, one_bf, one_bf,
                         one_bf, one_bf, one_bf, one_bf};

    // K staging map: 128 rows x 64 shorts; 4 chunks of 16B per thread
    const int srow = tid >> 3;          // 0..31 (row within 32-row group)
    const int scol = (tid & 7) << 3;    // col chunk (8 shorts = 16 B)

    #pragma unroll
    for (int sel = 0; sel < 2; ++sel) {
        const int qt = sel ? (nqt - 1 - p) : p;
        const int q0 = qt * 64;
        const int qbase = q0 + wave * 16;
        const int qabs = qbase + l16;       // this lane's q row (cols of S^T)

        // Q fragments (B-operand: n=l16, k=quad*8+j)
        const size_t rowQ = (size_t)(b * S + qbase + l16) * D_MODEL + h * D_K;
        const bf16x8 qf0 = *(const bf16x8*)(Qp + rowQ + quad * 8);
        const bf16x8 qf1 = *(const bf16x8*)(Qp + rowQ + 32 + quad * 8);

        floatx4 acc2[4];   // [d-tile]; C: col=d(l16), row=q(quad*4+r)
        floatx4 acc_l = zero4;
        #pragma unroll
        for (int dt = 0; dt < 4; ++dt) acc2[dt] = zero4;

        const int ni = (qt >> 1) + 1;

        // in-flight K tile registers (16 VGPR) + mask scalar
        bf16x8 kr[4];
        float mr = 0.f;

        // prologue: tile 0 -> regs -> Ks[0]
        #pragma unroll
        for (int c = 0; c < 4; ++c)
            kr[c] = *(const bf16x8*)(
                Kbase + (size_t)(c * 32 + srow) * D_MODEL + scol);
        if (tid < 128) mr = (mbase[tid] == 0) ? NEG_INF : 0.f;
        #pragma unroll
        for (int c = 0; c < 4; ++c)
            *(bf16x8*)(&Ks[0][(c * 32 + srow) * KS_PAD + scol]) = kr[c];
        if (tid < 128) mskf[0][tid] = mr;
        __syncthreads();

        for (int kt = 0; kt < ni; ++kt) {
            const int k0 = kt * 128;
            const int cur = kt & 1;
            const bool pre = (kt + 1 < ni);

            // issue next-tile K loads; latency hides under compute below
            if (pre) {
                const int kn = k0 + 128;
                #pragma unroll
                for (int c = 0; c < 4; ++c)
                    kr[c] = *(const bf16x8*)(
                        Kbase + (size_t)(kn + c * 32 + srow) * D_MODEL + scol);
                if (tid < 128) mr = (mbase[kn + tid] == 0) ? NEG_INF : 0.f;
            }

            // S^T = K Q^T + padding-mask-init: rows=keys, cols=q
            floatx4 s[8];
            #pragma unroll
            for (int nt = 0; nt < 8; ++nt) {
                floatx4 c = *(const floatx4*)(&mskf[cur][nt * 16 + quad * 4]);
                const unsigned short* kro = &Ks[cur][(nt * 16 + l16) * KS_PAD];
                bf16x8 kf0 = *(const bf16x8*)(kro + quad * 8);
                bf16x8 kf1 = *(const bf16x8*)(kro + 32 + quad * 8);
                c = __builtin_amdgcn_mfma_f32_16x16x32_bf16(kf0, qf0, c, 0, 0, 0);
                c = __builtin_amdgcn_mfma_f32_16x16x32_bf16(kf1, qf1, c, 0, 0, 0);
                s[nt] = c;
            }

            // causal mask: only the last k-tile of this q-tile needs it
            if (kt == ni - 1) {
                #pragma unroll
                for (int nt = 0; nt < 8; ++nt) {
                    const int kb = k0 + nt * 16 + quad * 4;
                    #pragma unroll
                    for (int r = 0; r < 4; ++r)
                        if (kb + r > qabs) s[nt][r] = NEG_INF;
                }
            }

            // P = exp2(s), truncation-packed to bf16 pairs in registers:
            // pk0[nt] = keys (quad*4+0, +1), pk1[nt] = keys (quad*4+2, +3)
            unsigned pk0[8], pk1[8];
            #pragma unroll
            for (int nt = 0; nt < 8; ++nt) {
                const float e0 = __builtin_exp2f(s[nt][0]);
                const float e1 = __builtin_exp2f(s[nt][1]);
                const float e2 = __builtin_exp2f(s[nt][2]);
                const float e3 = __builtin_exp2f(s[nt][3]);
                pk0[nt] = __builtin_amdgcn_perm(__builtin_bit_cast(unsigned, e1),
                                                __builtin_bit_cast(unsigned, e0), 0x07060302u);
                pk1[nt] = __builtin_amdgcn_perm(__builtin_bit_cast(unsigned, e3),
                                                __builtin_bit_cast(unsigned, e2), 0x07060302u);
            }

            // O += P V ; l += P 1   (K=128 keys -> 4 kh steps)
            // A-operand in-register via permlane32/16_swap; V B-operand read
            // directly from global (L1/L2-resident tile).
            const unsigned short* Vk = Vbase + k0;
            #pragma unroll
            for (int kh = 0; kh < 4; ++kh) {
                uintx2 a32 = __builtin_amdgcn_permlane32_swap(
                    pk0[2 * kh], pk0[2 * kh + 1], false, false);
                uintx2 b32 = __builtin_amdgcn_permlane32_swap(
                    pk1[2 * kh], pk1[2 * kh + 1], false, false);
                uintx2 a16 = __builtin_amdgcn_permlane16_swap(
                    a32[0], a32[1], false, false);
                uintx2 b16 = __builtin_amdgcn_permlane16_swap(
                    b32[0], b32[1], false, false);
                const uintx4 pw = {a16[0], b16[0], a16[1], b16[1]};
                const bf16x8 pf = __builtin_bit_cast(bf16x8, pw);
                #pragma unroll
                for (int dt = 0; dt < 4; ++dt) {
                    bf16x8 vf = *(const bf16x8*)(
                        Vk + (size_t)(dt * 16 + l16) * S + kh * 32 + quad * 8);
                    acc2[dt] = __builtin_amdgcn_mfma_f32_16x16x32_bf16(pf, vf, acc2[dt], 0, 0, 0);
                }
                acc_l = __builtin_amdgcn_mfma_f32_16x16x32_bf16(pf, ones, acc_l, 0, 0, 0);
            }

            // commit staged tile kt+1: regs -> Ks[cur^1] (write-late)
            if (pre) {
                #pragma unroll
                for (int c = 0; c < 4; ++c)
                    *(bf16x8*)(&Ks[cur ^ 1][(c * 32 + srow) * KS_PAD + scol]) = kr[c];
                if (tid < 128) mskf[cur ^ 1][tid] = mr;
            }
            __syncthreads();
        }

        // epilogue: O = acc / l
        #pragma unroll
        for (int r = 0; r < 4; ++r) {
            const float inv = 1.f / acc_l[r];
            const int gq = qbase + quad * 4 + r;
            const size_t base = (size_t)(b * S + gq) * D_MODEL + h * D_K;
            #pragma unroll
            for (int dt = 0; dt < 4; ++dt)
                O[base + dt * 16 + l16] = f2bf(acc2[dt][r] * inv);
        }
        __syncthreads();  // LDS reused by second tile
    }
}

// ---------------------------------------------------------------------------
extern "C" void kernel_launch(void* const* d_in, const int* in_sizes, int n_in,
                              void* d_out, int out_size, void* d_ws, size_t ws_size,
                              hipStream_t stream) {
    const float* query = (const float*)d_in[0];
    const float* key   = (const float*)d_in[1];
    const float* value = (const float*)d_in[2];
    const int*   mask  = (const int*)d_in[3];
    const float* Wq = (const float*)d_in[4];
    const float* bq = (const float*)d_in[5];
    const float* Wk = (const float*)d_in[6];
    const float* bk = (const float*)d_in[7];
    const float* Wv = (const float*)d_in[8];
    const float* bv = (const float*)d_in[9];
    const float* Wo = (const float*)d_in[10];
    const float* bo = (const float*)d_in[11];

    const int B  = 2;
    const int BS = in_sizes[3];
    const int S  = BS / B;
    const int M  = BS;

    unsigned short* Qp  = (unsigned short*)d_ws;
    unsigned short* Kp  = Qp  + (size_t)M * D_MODEL;
    unsigned short* VpT = Kp  + (size_t)M * D_MODEL;
    unsigned short* Obf = VpT + (size_t)M * D_MODEL;  // qa staging, then O
    unsigned short* Wbf = Obf + (size_t)M * D_MODEL;
    unsigned short* Wqb = Wbf;
    unsigned short* Wkb = Wbf + (size_t)W_ELEMS;
    unsigned short* Wvb = Wbf + (size_t)W_ELEMS * 2;
    unsigned short* Wob = Wbf + (size_t)W_ELEMS * 3;
    // d_out (25.2 MB fp32) doubles as scratch for ka/va bf16 until final GEMM
    unsigned short* ka = (unsigned short*)d_out;
    unsigned short* va = ka + (size_t)M * D_MODEL;

    dim3 blk(256);
    convert_w4<<<dim3(W_ELEMS / 1024, 4), blk, 0, stream>>>(Wq, Wk, Wv, Wo, Wbf);
    convert_a3<<<dim3((M * D_MODEL) / 1024, 3), blk, 0, stream>>>(
        query, key, value, Obf, ka, va);

    gemm128<true><<<dim3(M / 128, D_MODEL / 128, 3), blk, 0, stream>>>(
        Obf, ka, va, Wqb, Wkb, Wvb, bq, bk, bv, Qp, Kp, VpT, S);

    flash_attn<<<768, blk, 0, stream>>>(Qp, Kp, VpT, mask, Obf, S);

    gemm128<false><<<dim3(M / 128, D_MODEL / 128, 1), blk, 0, stream>>>(
        Obf, Obf, Obf, Wob, Wob, Wob, bo, bo, bo,
        d_out, d_out, d_out, S);
}

// Round 6
// 306.234 us; speedup vs baseline: 1.6418x; 1.6418x over previous
//
#include <hip/hip_runtime.h>
#include <hip/hip_bf16.h>

#define D_MODEL 768
#define N_HEADS 12
#define D_K     64
#define NEG_INF (-1e9f)
#define SCALE_Q 0.1803368801111154f  // 0.125 * log2(e): exp2-domain softmax
#define W_ELEMS (D_MODEL * D_MODEL)

typedef __attribute__((ext_vector_type(8))) short          bf16x8;
typedef __attribute__((ext_vector_type(4))) float          floatx4;
typedef __attribute__((ext_vector_type(4))) unsigned short ushortx4;
typedef __attribute__((ext_vector_type(2))) unsigned int   uintx2;
typedef __attribute__((ext_vector_type(4))) unsigned int   uintx4;

static __device__ __forceinline__ unsigned short f2bf(float f) {
    unsigned u = __builtin_bit_cast(unsigned, f);
    u += 0x7FFFu + ((u >> 16) & 1u);
    return (unsigned short)(u >> 16);
}

// async 16B/lane global->LDS (lds dest = wave-uniform base + lane*16)
static __device__ __forceinline__ void gload_lds16(const void* g, void* l) {
    __builtin_amdgcn_global_load_lds(
        (const __attribute__((address_space(1))) void*)g,
        (__attribute__((address_space(3))) void*)l, 16, 0, 0);
}

// ---------------------------------------------------------------------------
// fp32 -> bf16 converters.
// ---------------------------------------------------------------------------
__global__ __launch_bounds__(256) void convert_w4(
    const float* __restrict__ W0, const float* __restrict__ W1,
    const float* __restrict__ W2, const float* __restrict__ W3,
    unsigned short* __restrict__ out)
{
    const float* src[4] = {W0, W1, W2, W3};
    const float* W = src[blockIdx.y];
    unsigned short* o = out + (size_t)blockIdx.y * W_ELEMS;
    const int i = (blockIdx.x * 256 + threadIdx.x) * 4;
    float4 v = *(const float4*)(W + i);
    ushortx4 h = { f2bf(v.x), f2bf(v.y), f2bf(v.z), f2bf(v.w) };
    *(ushortx4*)(o + i) = h;
}

__global__ __launch_bounds__(256) void convert_a3(
    const float* __restrict__ A0, const float* __restrict__ A1,
    const float* __restrict__ A2,
    unsigned short* __restrict__ O0, unsigned short* __restrict__ O1,
    unsigned short* __restrict__ O2)
{
    const int z = blockIdx.y;
    const float* A = (z == 0) ? A0 : (z == 1) ? A1 : A2;
    unsigned short* O = (z == 0) ? O0 : (z == 1) ? O1 : O2;
    const int i = (blockIdx.x * 256 + threadIdx.x) * 4;
    float4 v = *(const float4*)(A + i);
    ushortx4 h = { f2bf(v.x), f2bf(v.y), f2bf(v.z), f2bf(v.w) };
    *(ushortx4*)(O + i) = h;
}

// ---------------------------------------------------------------------------
// C[M,N] = A[M,K] @ W[N,K]^T + bias[N];  A, W bf16; K = N = 768.
// m97 shape: 128x128 block tile, BK=32, 4 waves in 2x2 (64x64/wave),
// acc[4][4] -> 32 MFMA per barrier pair. Async global_load_lds staging.
// MFMA operand-swapped: D rows (quad*4+r) = n, cols (l16) = m -> vectorized
// stores along n. QKV: grid.z selects {Q(scale,bf16), K(bf16), V(->VpT)}.
// !QKV: single fp32 output (the final O @ Wo^T).
// ---------------------------------------------------------------------------
template <bool QKV>
__global__ __launch_bounds__(256) void gemm128(
    const unsigned short* __restrict__ A0, const unsigned short* __restrict__ A1,
    const unsigned short* __restrict__ A2,
    const unsigned short* __restrict__ W0, const unsigned short* __restrict__ W1,
    const unsigned short* __restrict__ W2,
    const float* __restrict__ b0, const float* __restrict__ b1,
    const float* __restrict__ b2,
    void* __restrict__ C0, void* __restrict__ C1, void* __restrict__ C2,
    int S)
{
    __shared__ __align__(16) unsigned short As[128 * 32];
    __shared__ __align__(16) unsigned short Bs[128 * 32];

    const int z = QKV ? blockIdx.z : 0;
    const unsigned short* A = (z == 0) ? A0 : (z == 1) ? A1 : A2;
    const unsigned short* W = (z == 0) ? W0 : (z == 1) ? W1 : W2;
    const float* bias       = (z == 0) ? b0 : (z == 1) ? b1 : b2;
    void* C                 = (z == 0) ? C0 : (z == 1) ? C1 : C2;
    const float scale = (QKV && z == 0) ? SCALE_Q : 1.0f;
    const int mode = QKV ? ((z == 2) ? 3 : 1) : 0;   // 3=VpT, 1=bf16, 0=fp32

    const int tid  = threadIdx.x;
    const int wave = tid >> 6;
    const int lane = tid & 63;
    const int quad = lane >> 4;
    const int l16  = lane & 15;
    const int m0 = blockIdx.x * 128;
    const int n0 = blockIdx.y * 128;
    const int wm = (wave & 1) * 64;
    const int wn = (wave >> 1) * 64;
    const int sr = lane >> 2;          // staging row within 16-row group
    const int sc = (lane & 3) << 3;    // staging col chunk (8 shorts = 16 B)

    const floatx4 zero4 = {0.f, 0.f, 0.f, 0.f};
    floatx4 acc[4][4];
    #pragma unroll
    for (int i = 0; i < 4; ++i)
        #pragma unroll
        for (int j = 0; j < 4; ++j) acc[i][j] = zero4;

    for (int k0 = 0; k0 < D_MODEL; k0 += 32) {
        // wave stages A rows [32w,32w+32) and W rows [32w,32w+32), 16/call
        #pragma unroll
        for (int c = 0; c < 2; ++c) {
            const int row = wave * 32 + c * 16;
            gload_lds16(A + (size_t)(m0 + row + sr) * D_MODEL + k0 + sc,
                        As + row * 32);
            gload_lds16(W + (size_t)(n0 + row + sr) * D_MODEL + k0 + sc,
                        Bs + row * 32);
        }
        __syncthreads();

        bf16x8 af[4], bfr[4];
        #pragma unroll
        for (int i = 0; i < 4; ++i)
            af[i] = *(const bf16x8*)(As + (wm + i * 16 + l16) * 32 + quad * 8);
        #pragma unroll
        for (int j = 0; j < 4; ++j)
            bfr[j] = *(const bf16x8*)(Bs + (wn + j * 16 + l16) * 32 + quad * 8);
        #pragma unroll
        for (int i = 0; i < 4; ++i)
            #pragma unroll
            for (int j = 0; j < 4; ++j)
                acc[i][j] = __builtin_amdgcn_mfma_f32_16x16x32_bf16(
                    bfr[j], af[i], acc[i][j], 0, 0, 0);   // swapped: rows=n
        __syncthreads();
    }

    // epilogue: D[i][j] rows (quad*4+r) = n, cols (l16) = m
    #pragma unroll
    for (int i = 0; i < 4; ++i) {
        const int m = m0 + wm + i * 16 + l16;
        #pragma unroll
        for (int j = 0; j < 4; ++j) {
            const int nb = n0 + wn + j * 16 + quad * 4;
            const float4 bv = *(const float4*)(bias + nb);
            float v0 = (acc[i][j][0] + bv.x) * scale;
            float v1 = (acc[i][j][1] + bv.y) * scale;
            float v2 = (acc[i][j][2] + bv.z) * scale;
            float v3 = (acc[i][j][3] + bv.w) * scale;
            if (mode == 0) {
                float4 o = {v0, v1, v2, v3};
                *(float4*)((float*)C + (size_t)m * D_MODEL + nb) = o;
            } else if (mode == 1) {
                ushortx4 o = {f2bf(v0), f2bf(v1), f2bf(v2), f2bf(v3)};
                *(ushortx4*)((unsigned short*)C + (size_t)m * D_MODEL + nb) = o;
            } else {
                // VpT[(bb*H + h)*64 + d][s]: 4 consecutive d, fixed s=m
                const int bb = m / S, s = m - bb * S;
                const int hh = nb >> 6, d = nb & 63;
                unsigned short* base = (unsigned short*)C +
                    ((size_t)(bb * N_HEADS + hh) * D_K + d) * S + s;
                base[0]         = f2bf(v0);
                base[(size_t)S]     = f2bf(v1);
                base[(size_t)S * 2] = f2bf(v2);
                base[(size_t)S * 3] = f2bf(v3);
            }
        }
    }
}

// ---------------------------------------------------------------------------
// Causal flash attention: 128-key k-iterations, load-balanced tile pairs
// (p, 63-p) -> every block runs exactly 33 k-iterations (grid 768 = 3
// blocks/CU). XCD swizzle: bh = L%24 keeps each (b,h)'s 32 blocks on one
// XCD's L2. Operand-swapped QK^T (rows=keys, cols=q), P-in-registers via
// permlane32/16_swap (T12), row-sum via ones-MFMA, fixed-m exp2 softmax.
//
// R6 vs R2 (structure identical, staging mechanism replaced):
//   K/V staged via async global_load_lds (width 16) instead of the
//   global->VGPR->LDS round trip. DMA dest must be linear (base+lane*16),
//   so the bank-conflict fix moves from pads to XOR swizzle applied by
//   PRE-SWIZZLING THE PER-LANE GLOBAL SOURCE address (m201/m173 pattern;
//   XOR is an involution so source-permute == read-permute):
//     conceptual (row, chunk p) holds global chunk p ^ (row&7)   [16B chunks]
//   K[128][64]: lane l call c stages row w*32+c*8+(l>>3), its global chunk
//   is (l&7)^(l>>3) -- per-lane constant. V[64][128]: row w*16+c*4+(l>>4),
//   global chunk (l&15)^((c&1)*4+(l>>4)). Reads XOR (row&7)<<3 -> 2-way
//   conflicts (free). Removes 16 VALU-fed LDS ops + vmcnt-coupled waits
//   per thread per iteration; frees staging VGPRs.
// ---------------------------------------------------------------------------
__global__ __launch_bounds__(256) void flash_attn(
    const unsigned short* __restrict__ Qp,
    const unsigned short* __restrict__ Kp,
    const unsigned short* __restrict__ VpT,
    const int* __restrict__ mask,
    unsigned short* __restrict__ O,   // bf16 [B*S, D_MODEL]
    int S)
{
    __shared__ __align__(16) unsigned short Ks [128 * 64];   // [key][d]  swz
    __shared__ __align__(16) unsigned short Vts[64 * 128];   // [d][key]  swz
    __shared__ __align__(16) float mskf[128];

    const int L  = blockIdx.x;
    const int bh = L % 24;
    const int p  = L / 24;
    const int h  = bh % 12;
    const int b  = bh / 12;
    const int nqt = S >> 6;
    const int tid  = threadIdx.x;
    const int wave = tid >> 6;
    const int lane = tid & 63;
    const int quad = lane >> 4;
    const int l16  = lane & 15;
    const int sx   = (l16 & 7) << 3;   // read-side swizzle field (shorts)

    const unsigned short* Kbase = Kp  + (size_t)(b * S) * D_MODEL + h * D_K;
    const unsigned short* Vbase = VpT + (size_t)(b * N_HEADS + h) * D_K * S;
    const int* mbase = mask + b * S;

    // DMA staging source maps (per-lane constants)
    const int kgrow = wave * 32 + (lane >> 3);            // + c*8
    const int kgcol = ((lane & 7) ^ (lane >> 3)) << 3;
    const int vgrow = wave * 16 + (lane >> 4);            // + c*4
    const int vgc_e = ((lane & 15) ^ (lane >> 4)) << 3;        // even c
    const int vgc_o = ((lane & 15) ^ (4 + (lane >> 4))) << 3;  // odd  c

    const floatx4 zero4 = {0.f, 0.f, 0.f, 0.f};
    const short one_bf = (short)0x3F80;  // bf16 1.0
    const bf16x8 ones = {one_bf, one_bf, one_bf, one_bf,
                         one_bf, one_bf, one_bf, one_bf};

    #pragma unroll
    for (int sel = 0; sel < 2; ++sel) {
        const int qt = sel ? (nqt - 1 - p) : p;
        const int q0 = qt * 64;
        const int qbase = q0 + wave * 16;
        const int qabs = qbase + l16;       // this lane's q row (cols of S^T)

        // Q fragments (B-operand: n=l16, k=quad*8+j)
        const size_t rowQ = (size_t)(b * S + qbase + l16) * D_MODEL + h * D_K;
        const bf16x8 qf0 = *(const bf16x8*)(Qp + rowQ + quad * 8);
        const bf16x8 qf1 = *(const bf16x8*)(Qp + rowQ + 32 + quad * 8);

        floatx4 acc2[4];   // [d-tile]; C: col=d(l16), row=q(quad*4+r)
        floatx4 acc_l = zero4;
        #pragma unroll
        for (int dt = 0; dt < 4; ++dt) acc2[dt] = zero4;

        const int ni = (qt >> 1) + 1;
        for (int kt = 0; kt < ni; ++kt) {
            const int k0 = kt * 128;
            // stage K [128 keys][64 d] and V^T [64 d][128 keys] via async
            // DMA, source pre-swizzled (see header comment)
            #pragma unroll
            for (int c = 0; c < 4; ++c) {
                gload_lds16(
                    Kbase + (size_t)(k0 + kgrow + c * 8) * D_MODEL + kgcol,
                    (char*)Ks + (wave * 4 + c) * 1024);
                const int vg = (c & 1) ? vgc_o : vgc_e;
                gload_lds16(
                    Vbase + (size_t)(vgrow + c * 4) * S + k0 + vg,
                    (char*)Vts + (wave * 4 + c) * 1024);
            }
            if (tid < 128)
                mskf[tid] = (mbase[k0 + tid] == 0) ? NEG_INF : 0.f;
            __syncthreads();

            // S^T = K Q^T + padding-mask-init: rows=keys, cols=q
            floatx4 s[8];
            #pragma unroll
            for (int nt = 0; nt < 8; ++nt) {
                floatx4 c = *(const floatx4*)(mskf + nt * 16 + quad * 4);
                const unsigned short* kro = Ks + (nt * 16 + l16) * 64;
                bf16x8 kf0 = *(const bf16x8*)(kro + ((quad * 8) ^ sx));
                bf16x8 kf1 = *(const bf16x8*)(kro + ((32 + quad * 8) ^ sx));
                c = __builtin_amdgcn_mfma_f32_16x16x32_bf16(kf0, qf0, c, 0, 0, 0);
                c = __builtin_amdgcn_mfma_f32_16x16x32_bf16(kf1, qf1, c, 0, 0, 0);
                s[nt] = c;
            }

            // causal mask: only the last k-tile of this q-tile needs it
            if (kt == ni - 1) {
                #pragma unroll
                for (int nt = 0; nt < 8; ++nt) {
                    const int kb = k0 + nt * 16 + quad * 4;
                    #pragma unroll
                    for (int r = 0; r < 4; ++r)
                        if (kb + r > qabs) s[nt][r] = NEG_INF;
                }
            }

            // P = exp2(s), truncation-packed to bf16 pairs in registers:
            // pk0[nt] = keys (quad*4+0, +1), pk1[nt] = keys (quad*4+2, +3)
            unsigned pk0[8], pk1[8];
            #pragma unroll
            for (int nt = 0; nt < 8; ++nt) {
                const float e0 = __builtin_exp2f(s[nt][0]);
                const float e1 = __builtin_exp2f(s[nt][1]);
                const float e2 = __builtin_exp2f(s[nt][2]);
                const float e3 = __builtin_exp2f(s[nt][3]);
                pk0[nt] = __builtin_amdgcn_perm(__builtin_bit_cast(unsigned, e1),
                                                __builtin_bit_cast(unsigned, e0), 0x07060302u);
                pk1[nt] = __builtin_amdgcn_perm(__builtin_bit_cast(unsigned, e3),
                                                __builtin_bit_cast(unsigned, e2), 0x07060302u);
            }

            // O += P V ; l += P 1   (K=128 keys -> 4 kh steps)
            // A-operand built in-register: cross-quad redistribution at fixed
            // l16 via permlane32_swap + permlane16_swap (no LDS).
            #pragma unroll
            for (int kh = 0; kh < 4; ++kh) {
                uintx2 a32 = __builtin_amdgcn_permlane32_swap(
                    pk0[2 * kh], pk0[2 * kh + 1], false, false);
                uintx2 b32 = __builtin_amdgcn_permlane32_swap(
                    pk1[2 * kh], pk1[2 * kh + 1], false, false);
                uintx2 a16 = __builtin_amdgcn_permlane16_swap(
                    a32[0], a32[1], false, false);
                uintx2 b16 = __builtin_amdgcn_permlane16_swap(
                    b32[0], b32[1], false, false);
                const uintx4 pw = {a16[0], b16[0], a16[1], b16[1]};
                const bf16x8 pf = __builtin_bit_cast(bf16x8, pw);
                #pragma unroll
                for (int dt = 0; dt < 4; ++dt) {
                    const unsigned short* vro = Vts + (dt * 16 + l16) * 128;
                    bf16x8 vf = *(const bf16x8*)(vro + ((kh * 32 + quad * 8) ^ sx));
                    acc2[dt] = __builtin_amdgcn_mfma_f32_16x16x32_bf16(pf, vf, acc2[dt], 0, 0, 0);
                }
                acc_l = __builtin_amdgcn_mfma_f32_16x16x32_bf16(pf, ones, acc_l, 0, 0, 0);
            }
            __syncthreads();
        }

        // epilogue: O = acc / l
        #pragma unroll
        for (int r = 0; r < 4; ++r) {
            const float inv = 1.f / acc_l[r];
            const int gq = qbase + quad * 4 + r;
            const size_t base = (size_t)(b * S + gq) * D_MODEL + h * D_K;
            #pragma unroll
            for (int dt = 0; dt < 4; ++dt)
                O[base + dt * 16 + l16] = f2bf(acc2[dt][r] * inv);
        }
        __syncthreads();  // LDS reused by second tile
    }
}

// ---------------------------------------------------------------------------
extern "C" void kernel_launch(void* const* d_in, const int* in_sizes, int n_in,
                              void* d_out, int out_size, void* d_ws, size_t ws_size,
                              hipStream_t stream) {
    const float* query = (const float*)d_in[0];
    const float* key   = (const float*)d_in[1];
    const float* value = (const float*)d_in[2];
    const int*   mask  = (const int*)d_in[3];
    const float* Wq = (const float*)d_in[4];
    const float* bq = (const float*)d_in[5];
    const float* Wk = (const float*)d_in[6];
    const float* bk = (const float*)d_in[7];
    const float* Wv = (const float*)d_in[8];
    const float* bv = (const float*)d_in[9];
    const float* Wo = (const float*)d_in[10];
    const float* bo = (const float*)d_in[11];

    const int B  = 2;
    const int BS = in_sizes[3];
    const int S  = BS / B;
    const int M  = BS;

    unsigned short* Qp  = (unsigned short*)d_ws;
    unsigned short* Kp  = Qp  + (size_t)M * D_MODEL;
    unsigned short* VpT = Kp  + (size_t)M * D_MODEL;
    unsigned short* Obf = VpT + (size_t)M * D_MODEL;  // qa staging, then O
    unsigned short* Wbf = Obf + (size_t)M * D_MODEL;
    unsigned short* Wqb = Wbf;
    unsigned short* Wkb = Wbf + (size_t)W_ELEMS;
    unsigned short* Wvb = Wbf + (size_t)W_ELEMS * 2;
    unsigned short* Wob = Wbf + (size_t)W_ELEMS * 3;
    // d_out (25.2 MB fp32) doubles as scratch for ka/va bf16 until final GEMM
    unsigned short* ka = (unsigned short*)d_out;
    unsigned short* va = ka + (size_t)M * D_MODEL;

    dim3 blk(256);
    convert_w4<<<dim3(W_ELEMS / 1024, 4), blk, 0, stream>>>(Wq, Wk, Wv, Wo, Wbf);
    convert_a3<<<dim3((M * D_MODEL) / 1024, 3), blk, 0, stream>>>(
        query, key, value, Obf, ka, va);

    gemm128<true><<<dim3(M / 128, D_MODEL / 128, 3), blk, 0, stream>>>(
        Obf, ka, va, Wqb, Wkb, Wvb, bq, bk, bv, Qp, Kp, VpT, S);

    flash_attn<<<768, blk, 0, stream>>>(Qp, Kp, VpT, mask, Obf, S);

    gemm128<false><<<dim3(M / 128, D_MODEL / 128, 1), blk, 0, stream>>>(
        Obf, Obf, Obf, Wob, Wob, Wob, bo, bo, bo,
        d_out, d_out, d_out, S);
}